// Round 5
// baseline (565.757 us; speedup 1.0000x reference)
//
#include <hip/hip_runtime.h>
#include <hip/hip_bf16.h>

// CosformerAttention: L=4096, B=4, E=1024, H=16, HD=64, n=B*H=64 heads.
// Round 12:
//  k_gemmB : 2-phase double-buffered LDS pipeline (stage next tile BEFORE
//            computing current; one __syncthreads per K-step whose implicit
//            vmcnt(0) drain lands AFTER compute). 32KB LDS.
//  k_attn3 : 64 rows/block, 4x4 register patch (FMA/ds_read 5.7 -> 8.9,
//            LDS-pipe floor ~61us vs measured 103 at 2x4).
//  k_kv3/k_kvred/k_cvtW/k_cvtX: unchanged.
// Order: cvtW(k),cvtX(k),gemm->Kb | cvtW(v),cvtX(v),gemm->Vb |
//        kv3 -> partials (d_out) | kvred -> kvm/kvd | cvtW(q),cvtX(q),
//        gemm->d_out | attn3 in-place.

typedef unsigned short ushortt;
typedef unsigned int u32;
typedef __attribute__((ext_vector_type(8))) short bf16x8;
typedef __attribute__((ext_vector_type(4))) float f32x4;

#define L_DIM 4096
#define B_DIM 4
#define E_DIM 1024

#define KV_CH 8                    // L chunks for k_kv3
#define KV_LCH (L_DIM / KV_CH)     // 512 rows per chunk
#define KV_LT 32                   // l-tile rows staged in LDS

__device__ __forceinline__ ushortt f2bf(float f) {
    union { float f; u32 u; } v; v.f = f;
    u32 u = v.u;
    u += 0x7FFFu + ((u >> 16) & 1u);   // round-to-nearest-even
    return (ushortt)(u >> 16);
}
__device__ __forceinline__ float bf2f(ushortt h) {
    union { u32 u; float f; } v; v.u = ((u32)h) << 16;
    return v.f;
}

__device__ __forceinline__ void gl_lds16(const void* g, void* l) {
    __builtin_amdgcn_global_load_lds(
        (const __attribute__((address_space(1))) unsigned int*)g,
        (__attribute__((address_space(3))) unsigned int*)l, 16, 0, 0);
}

// ---------------- f32 -> bf16 converters -------------------------------------
__global__ __launch_bounds__(256) void k_cvtW(
    const float* __restrict__ W, ushortt* __restrict__ Wb)
{
    const int i = (blockIdx.x * 256 + threadIdx.x) * 4;   // 1M elems
    const float4 v = *reinterpret_cast<const float4*>(W + i);
    ushortt o[4] = { f2bf(v.x), f2bf(v.y), f2bf(v.z), f2bf(v.w) };
    *reinterpret_cast<uint2*>(Wb + i) = *reinterpret_cast<uint2*>(o);
}

__global__ __launch_bounds__(256) void k_cvtX(
    const float* __restrict__ X, ushortt* __restrict__ Xb)
{
    const int i = (blockIdx.x * 256 + threadIdx.x) * 4;   // 16.8M elems
    const float4 v = *reinterpret_cast<const float4*>(X + i);
    ushortt o[4] = { f2bf(v.x), f2bf(v.y), f2bf(v.z), f2bf(v.w) };
    *reinterpret_cast<uint2*>(Xb + i) = *reinterpret_cast<uint2*>(o);
}

// ---------------- MFMA projection GEMM (bf16 A and B, 2-phase pipeline) ------
// Y[m][n] = relu?(sum_k Xb[m][k]*Wb[n][k] + b[n]); M=16384, N=1024, K=1024.
// Tile 128x128, BK=32, double-buffered. 4 waves (2x2), each wave 64x64 via
// 4x4 of 16x16x32 MFMA. XOR swizzle ((row>>1)&3)<<4 via pre-swizzled global
// source (linear gl_lds dest) + same XOR on ds_read.
__global__ __launch_bounds__(256) void k_gemmB(
    const ushortt* __restrict__ Xb, const ushortt* __restrict__ Wb,
    const float* __restrict__ bias,
    float* __restrict__ Of, ushortt* __restrict__ Ob, const int p)
{
    __shared__ char sA[2][8192];   // 2 x 128 rows x 64B
    __shared__ char sB[2][8192];

    const int t = threadIdx.x;
    const int ln = t & 63;
    const int wv = t >> 6;
    const int wr = wv >> 1, wc = wv & 1;

    // XCD-aware bijective swizzle: 1024 blocks, xcd = orig%8 gets 128 contiguous.
    const int orig = blockIdx.x;
    const int bid = (orig & 7) * 128 + (orig >> 3);
    const int mblk = (bid >> 3) * 128;
    const int nblk = (bid & 7) * 128;

    f32x4 acc[4][4];
#pragma unroll
    for (int i = 0; i < 4; i++)
#pragma unroll
        for (int j = 0; j < 4; j++) acc[i][j] = (f32x4){0.f, 0.f, 0.f, 0.f};

    // staging lane constants (16 rows of 64B per 1KB chunk)
    const int rowIn = ln >> 2;                              // 0..15
    const int srcE  = ((ln & 3) ^ ((ln >> 3) & 3)) << 3;    // bf16 elems, pre-swizzled

    // frag-read lane constants
    const int g   = ln >> 4;
    const int r15 = ln & 15;
    const int sw  = ((r15 >> 1) & 3) << 4;                  // ((row>>1)&3)<<4

    auto stage = [&](int buf, int k0) {
#pragma unroll
        for (int c = 0; c < 2; c++) {
            const int ch = wv * 2 + c;
            const int row = ch * 16 + rowIn;
            gl_lds16(Xb + (size_t)(mblk + row) * E_DIM + k0 + srcE, &sA[buf][ch * 1024]);
            gl_lds16(Wb + (size_t)(nblk + row) * E_DIM + k0 + srcE, &sB[buf][ch * 1024]);
        }
    };

    // prologue: fill buffer 0 (implicit vmcnt(0)+lgkmcnt(0) drain in barrier)
    stage(0, 0);
    __syncthreads();

    int cur = 0;
    for (int k0 = 0; k0 < 1024; k0 += 32) {
        // issue next tile's loads FIRST — they fly during this tile's compute
        if (k0 + 32 < 1024) stage(cur ^ 1, k0 + 32);

        bf16x8 va[4], vb[4];
#pragma unroll
        for (int i = 0; i < 4; i++) {
            const int row = wr * 64 + i * 16 + r15;
            va[i] = *reinterpret_cast<const bf16x8*>(&sA[cur][row * 64 + ((g * 16) ^ sw)]);
        }
#pragma unroll
        for (int j = 0; j < 4; j++) {
            const int n = wc * 64 + j * 16 + r15;
            vb[j] = *reinterpret_cast<const bf16x8*>(&sB[cur][n * 64 + ((g * 16) ^ sw)]);
        }
#pragma unroll
        for (int i = 0; i < 4; i++)
#pragma unroll
            for (int j = 0; j < 4; j++)
                acc[i][j] = __builtin_amdgcn_mfma_f32_16x16x32_bf16(va[i], vb[j], acc[i][j], 0, 0, 0);

        // one barrier per K-step; its implicit vmcnt(0) waits for the staged
        // loads only now, after compute
        __syncthreads();
        cur ^= 1;
    }

    // ---- epilogue: C row = (lane>>4)*4 + reg, col = lane&15 (m89 mapping) ----
#pragma unroll
    for (int j = 0; j < 4; j++) {
        const int col = nblk + wc * 64 + j * 16 + r15;
        const float bj = bias[col];
#pragma unroll
        for (int i = 0; i < 4; i++) {
            const int row0 = mblk + wr * 64 + i * 16 + g * 4;
#pragma unroll
            for (int r = 0; r < 4; r++) {
                float v = acc[i][j][r] + bj;
                if (p < 2) v = fmaxf(v, 0.0f);
                if (p == 0) Of[(size_t)(row0 + r) * E_DIM + col] = v;
                else        Ob[(size_t)(row0 + r) * E_DIM + col] = f2bf(v);
            }
        }
    }
}

// ---------------- kv partials: pm[ch][head][128][64], pd[ch][head][128] ------
// pm = sum_{l in chunk} sk[l][d]*v[l][m]; pd = sum sk[l][d]. Plain stores.
__global__ __launch_bounds__(256) void k_kv3(
    const ushortt* __restrict__ Kb, const ushortt* __restrict__ Vb,
    float* __restrict__ pm, float* __restrict__ pd)
{
    __shared__ float sk[KV_LT][128];   // feature-mapped K tile
    __shared__ float sv[KV_LT][64];    // V tile

    const int head = blockIdx.x;
    const int b = head >> 4, hh = head & 15;
    const int t = threadIdx.x;
    const int mq = t & 7;              // m base = mq*8
    const int dq = t >> 3;             // d base = dq*4
    const int l0base = blockIdx.y * KV_LCH;

    float acc[4][8];
    float ksum[4];
#pragma unroll
    for (int i = 0; i < 4; i++) {
        ksum[i] = 0.0f;
#pragma unroll
        for (int j = 0; j < 8; j++) acc[i][j] = 0.0f;
    }

    const size_t headoff = (size_t)hh * 64;

    for (int l0 = l0base; l0 < l0base + KV_LCH; l0 += KV_LT) {
        __syncthreads();
#pragma unroll
        for (int i = 0; i < 2; i++) {
            const int j = t + 256 * i;         // 0..511
            const int l = j >> 4;              // 0..31
            const int c4 = (j & 15) << 2;      // 0,4,...,60
            const size_t rowb = ((size_t)(l0 + l) * B_DIM + b) * E_DIM + headoff;
            const uint2 kraw = *reinterpret_cast<const uint2*>(Kb + rowb + c4);
            const uint2 vraw = *reinterpret_cast<const uint2*>(Vb + rowb + c4);
            const float ang = 1.5707963267948966f * (float)(l0 + l + 1) * (1.0f / 4096.0f);
            const float sn = sinf(ang), cs = cosf(ang);
            const float k0 = bf2f((ushortt)(kraw.x & 0xffffu));
            const float k1 = bf2f((ushortt)(kraw.x >> 16));
            const float k2 = bf2f((ushortt)(kraw.y & 0xffffu));
            const float k3 = bf2f((ushortt)(kraw.y >> 16));
            *reinterpret_cast<float4*>(&sk[l][c4]) =
                make_float4(sn * k0, sn * k1, sn * k2, sn * k3);
            *reinterpret_cast<float4*>(&sk[l][64 + c4]) =
                make_float4(cs * k0, cs * k1, cs * k2, cs * k3);
            *reinterpret_cast<float4*>(&sv[l][c4]) =
                make_float4(bf2f((ushortt)(vraw.x & 0xffffu)),
                            bf2f((ushortt)(vraw.x >> 16)),
                            bf2f((ushortt)(vraw.y & 0xffffu)),
                            bf2f((ushortt)(vraw.y >> 16)));
        }
        __syncthreads();
#pragma unroll 8
        for (int l = 0; l < KV_LT; l++) {
            const float4 a4 = *reinterpret_cast<const float4*>(&sk[l][dq << 2]);
            const float4 v0 = *reinterpret_cast<const float4*>(&sv[l][mq << 3]);
            const float4 v1 = *reinterpret_cast<const float4*>(&sv[l][(mq << 3) + 4]);
            const float av[4] = { a4.x, a4.y, a4.z, a4.w };
            const float vv[8] = { v0.x, v0.y, v0.z, v0.w, v1.x, v1.y, v1.z, v1.w };
#pragma unroll
            for (int i = 0; i < 4; i++) {
#pragma unroll
                for (int j = 0; j < 8; j++) acc[i][j] += av[i] * vv[j];
                ksum[i] += av[i];
            }
        }
    }

    float* dstm = pm + ((size_t)blockIdx.y * 64 + head) * 8192;   // 128*64
    float* dstd = pd + ((size_t)blockIdx.y * 64 + head) * 128;
    const int d0 = dq << 2, m0 = mq << 3;
#pragma unroll
    for (int i = 0; i < 4; i++) {
        *reinterpret_cast<float4*>(&dstm[(d0 + i) * 64 + m0]) =
            make_float4(acc[i][0], acc[i][1], acc[i][2], acc[i][3]);
        *reinterpret_cast<float4*>(&dstm[(d0 + i) * 64 + m0 + 4]) =
            make_float4(acc[i][4], acc[i][5], acc[i][6], acc[i][7]);
        if (mq == 0) dstd[d0 + i] = ksum[i];
    }
}

// ---------------- reduce partials: kvm[head][128][64], kvd[head][128] --------
__global__ __launch_bounds__(256) void k_kvred(
    const float* __restrict__ pm, const float* __restrict__ pd,
    float* __restrict__ kvm, float* __restrict__ kvd)
{
    const int bid = blockIdx.x, t = threadIdx.x;
    if (bid < 512) {
        const int g = bid * 256 + t;           // float4 index, 131072 total
        const int head = g >> 11, r = g & 2047;
        float4 s = make_float4(0.f, 0.f, 0.f, 0.f);
#pragma unroll
        for (int c = 0; c < KV_CH; c++) {
            const float4 v = reinterpret_cast<const float4*>(pm)[((size_t)(c * 64 + head) << 11) + r];
            s.x += v.x; s.y += v.y; s.z += v.z; s.w += v.w;
        }
        reinterpret_cast<float4*>(kvm)[g] = s;
    } else {
#pragma unroll
        for (int it = 0; it < 8; it++) {
            const int idx = it * 256 + t;      // float4 index, 2048 total
            const int head = idx >> 5, r = idx & 31;
            float4 s = make_float4(0.f, 0.f, 0.f, 0.f);
#pragma unroll
            for (int c = 0; c < KV_CH; c++) {
                const float4 v = reinterpret_cast<const float4*>(pd)[((size_t)(c * 64 + head) << 5) + r];
                s.x += v.x; s.y += v.y; s.z += v.z; s.w += v.w;
            }
            reinterpret_cast<float4*>(kvd)[idx] = s;
        }
    }
}

// ---------------- attn: out = (q_ . kv) / max(q_ . ksum, eps) ----------------
// Block = (head, 64 l-rows). LDS: skv[128][64] 32KB + skd[128] + sq[64][132]
// (33.8KB) = 66.4KB -> 2 blocks/CU. Thread patch 4 rows x 4 m (16x16 groups).
// In-place safe: block stages its own qout slice, barrier, then overwrites it.
__global__ __launch_bounds__(256) void k_attn3(
    float* qout, const float* __restrict__ kvm, const float* __restrict__ kvd)
{
    __shared__ float skv[128][64];
    __shared__ float skd[128];
    __shared__ float sq[64][132];

    const int t = threadIdx.x;
    const int head = blockIdx.x;           // 0..63
    const int b = head >> 4, hh = head & 15;
    const int l0 = blockIdx.y * 64;

    const float* kvh = kvm + (size_t)head * (128 * 64);

    // stage kv head-tile: 128 rows x 16 float4 (aligned, coalesced)
#pragma unroll
    for (int c = 0; c < 8; c++) {
        const int idx = t + 256 * c;       // 0..2047
        const int d = idx >> 4, m4 = (idx & 15) << 2;
        *reinterpret_cast<float4*>(&skv[d][m4]) =
            *reinterpret_cast<const float4*>(kvh + d * 64 + m4);
    }
    if (t < 128) skd[t] = kvd[(size_t)head * 128 + t];

    // stage 64 q rows with sin/cos feature map folded in
    const size_t qbase = ((size_t)l0 * B_DIM + b) * E_DIM + (size_t)hh * 64;
#pragma unroll
    for (int c = 0; c < 4; c++) {
        const int idx = t + 256 * c;       // 0..1023
        const int l = idx >> 4, q4 = (idx & 15) << 2;
        const float4 v = *reinterpret_cast<const float4*>(
            qout + qbase + (size_t)l * (B_DIM * E_DIM) + q4);
        const float ang = 1.5707963267948966f * (float)(l0 + l + 1) * (1.0f / 4096.0f);
        const float sn = sinf(ang), cs = cosf(ang);
        *reinterpret_cast<float4*>(&sq[l][q4]) =
            make_float4(sn * v.x, sn * v.y, sn * v.z, sn * v.w);
        *reinterpret_cast<float4*>(&sq[l][64 + q4]) =
            make_float4(cs * v.x, cs * v.y, cs * v.z, cs * v.w);
    }
    __syncthreads();

    const int tx = t & 15, ty = t >> 4;
    const int r = ty * 4, m0 = tx * 4;

    float4 acc[4];
    float accd[4];
#pragma unroll
    for (int i = 0; i < 4; i++) {
        acc[i] = make_float4(0.f, 0.f, 0.f, 0.f);
        accd[i] = 0.f;
    }

#pragma unroll 4
    for (int d0 = 0; d0 < 128; d0 += 4) {
        const float4 kd4 = *reinterpret_cast<const float4*>(&skd[d0]);
        float4 qv[4];
#pragma unroll
        for (int i = 0; i < 4; i++)
            qv[i] = *reinterpret_cast<const float4*>(&sq[r + i][d0]);
#pragma unroll
        for (int dd = 0; dd < 4; dd++) {
            const float4 kvv = *reinterpret_cast<const float4*>(&skv[d0 + dd][m0]);
            const float kdv = (dd == 0) ? kd4.x : (dd == 1) ? kd4.y : (dd == 2) ? kd4.z : kd4.w;
#pragma unroll
            for (int i = 0; i < 4; i++) {
                const float qs = (dd == 0) ? qv[i].x : (dd == 1) ? qv[i].y
                               : (dd == 2) ? qv[i].z : qv[i].w;
                acc[i].x += qs * kvv.x;
                acc[i].y += qs * kvv.y;
                acc[i].z += qs * kvv.z;
                acc[i].w += qs * kvv.w;
                accd[i] += qs * kdv;
            }
        }
    }

#pragma unroll
    for (int i = 0; i < 4; i++) {
        const float z = 1.0f / fmaxf(accd[i], 1e-4f);
        float4 vo = make_float4(acc[i].x * z, acc[i].y * z, acc[i].z * z, acc[i].w * z);
        *reinterpret_cast<float4*>(
            qout + qbase + (size_t)(r + i) * (B_DIM * E_DIM) + m0) = vo;
    }
}

extern "C" void kernel_launch(void* const* d_in, const int* in_sizes, int n_in,
                              void* d_out, int out_size, void* d_ws, size_t ws_size,
                              hipStream_t stream) {
    (void)in_sizes; (void)n_in; (void)out_size; (void)ws_size;
    const float* xq = (const float*)d_in[0];
    const float* xk = (const float*)d_in[1];
    const float* xv = (const float*)d_in[2];
    const float* wq = (const float*)d_in[3];
    const float* bq = (const float*)d_in[4];
    const float* wk = (const float*)d_in[5];
    const float* bk = (const float*)d_in[6];
    const float* wv = (const float*)d_in[7];
    const float* bv = (const float*)d_in[8];
    float* out = (float*)d_out;  // 67MB; free as scratch until Q-proj (runs last)

    char* ws = (char*)d_ws;
    // ws (69.24MB): [0,33.5M) Kb / later Xqb ; [33.5M,67.1M) Vb / later Wqb ;
    // [67.1M, +2.13M) Wb (K/V phase) / later kvm+kvd.
    ushortt* Kb  = (ushortt*)(ws);
    ushortt* Vb  = (ushortt*)(ws + 33554432);
    ushortt* Wb  = (ushortt*)(ws + 67108864);
    float*   kvm = (float*)(ws + 67108864);
    float*   kvd = (float*)(ws + 67108864 + 2097152);
    ushortt* Xqb = (ushortt*)(ws);              // over dead Kb
    ushortt* Wqb = (ushortt*)(ws + 33554432);   // over dead Vb

    // d_out scratch: [0,33.5M) Xkb / later pm+pd ; [33.5M,67.1M) Xvb.
    ushortt* Xkb = (ushortt*)d_out;
    ushortt* Xvb = (ushortt*)((char*)d_out + 33554432);
    float*   pm  = (float*)d_out;                              // 16.78MB
    float*   pd  = (float*)((char*)d_out + 16777216);          // 262KB

    dim3 blk(256);
    // K projection
    k_cvtW<<<dim3(1024), blk, 0, stream>>>(wk, Wb);
    k_cvtX<<<dim3(16384), blk, 0, stream>>>(xk, Xkb);
    k_gemmB<<<dim3(1024), blk, 0, stream>>>(Xkb, Wb, bk, (float*)nullptr, Kb, 1);
    // V projection
    k_cvtW<<<dim3(1024), blk, 0, stream>>>(wv, Wb);
    k_cvtX<<<dim3(16384), blk, 0, stream>>>(xv, Xvb);
    k_gemmB<<<dim3(1024), blk, 0, stream>>>(Xvb, Wb, bv, (float*)nullptr, Vb, 2);
    // kv partials (plain stores into d_out) + reduce into ws (over dead Wb)
    k_kv3<<<dim3(64, KV_CH), blk, 0, stream>>>(Kb, Vb, pm, pd);
    k_kvred<<<dim3(513), blk, 0, stream>>>(pm, pd, kvm, kvd);
    // Q projection (scratch in dead Kb/Vb regions; output fills d_out)
    k_cvtW<<<dim3(1024), blk, 0, stream>>>(wq, Wqb);
    k_cvtX<<<dim3(16384), blk, 0, stream>>>(xq, Xqb);
    k_gemmB<<<dim3(1024), blk, 0, stream>>>(Xqb, Wqb, bq, out, (ushortt*)nullptr, 0);
    // attention epilogue, in-place on d_out
    k_attn3<<<dim3(64, 64), blk, 0, stream>>>(out, kvm, kvd);
}

// Round 6
// 556.985 us; speedup vs baseline: 1.0157x; 1.0157x over previous
//
#include <hip/hip_runtime.h>
#include <hip/hip_bf16.h>

// CosformerAttention: L=4096, B=4, E=1024, H=16, HD=64, n=B*H=64 heads.
// Round 13: counted-vmcnt software pipeline in k_gemmB (T4). The round-12
// 2-phase dbuf was neutral because __syncthreads' implicit vmcnt(0) drained
// the just-issued prefetch every K-step. Now: 2-deep prefetch, raw s_barrier,
// s_waitcnt vmcnt(4) in steady state (never 0 until the last tile), two
// barriers per step (data-ready / buffer-reuse).
//  k_attn3/k_kv3/k_kvred/k_cvtW/k_cvtX: unchanged from round 12.

typedef unsigned short ushortt;
typedef unsigned int u32;
typedef __attribute__((ext_vector_type(8))) short bf16x8;
typedef __attribute__((ext_vector_type(4))) float f32x4;

#define L_DIM 4096
#define B_DIM 4
#define E_DIM 1024

#define KV_CH 8                    // L chunks for k_kv3
#define KV_LCH (L_DIM / KV_CH)     // 512 rows per chunk
#define KV_LT 32                   // l-tile rows staged in LDS

__device__ __forceinline__ ushortt f2bf(float f) {
    union { float f; u32 u; } v; v.f = f;
    u32 u = v.u;
    u += 0x7FFFu + ((u >> 16) & 1u);   // round-to-nearest-even
    return (ushortt)(u >> 16);
}
__device__ __forceinline__ float bf2f(ushortt h) {
    union { u32 u; float f; } v; v.u = ((u32)h) << 16;
    return v.f;
}

__device__ __forceinline__ void gl_lds16(const void* g, void* l) {
    __builtin_amdgcn_global_load_lds(
        (const __attribute__((address_space(1))) unsigned int*)g,
        (__attribute__((address_space(3))) unsigned int*)l, 16, 0, 0);
}

// ---------------- f32 -> bf16 converters -------------------------------------
__global__ __launch_bounds__(256) void k_cvtW(
    const float* __restrict__ W, ushortt* __restrict__ Wb)
{
    const int i = (blockIdx.x * 256 + threadIdx.x) * 4;   // 1M elems
    const float4 v = *reinterpret_cast<const float4*>(W + i);
    ushortt o[4] = { f2bf(v.x), f2bf(v.y), f2bf(v.z), f2bf(v.w) };
    *reinterpret_cast<uint2*>(Wb + i) = *reinterpret_cast<uint2*>(o);
}

__global__ __launch_bounds__(256) void k_cvtX(
    const float* __restrict__ X, ushortt* __restrict__ Xb)
{
    const int i = (blockIdx.x * 256 + threadIdx.x) * 4;   // 16.8M elems
    const float4 v = *reinterpret_cast<const float4*>(X + i);
    ushortt o[4] = { f2bf(v.x), f2bf(v.y), f2bf(v.z), f2bf(v.w) };
    *reinterpret_cast<uint2*>(Xb + i) = *reinterpret_cast<uint2*>(o);
}

// ---------------- MFMA projection GEMM (bf16, counted-vmcnt pipeline) --------
// Y[m][n] = relu?(sum_k Xb[m][k]*Wb[n][k] + b[n]); M=16384, N=1024, K=1024.
// Tile 128x128, BK=32, 32 K-tiles. 4 waves (2x2), each 64x64 via 4x4 MFMA.
// Pipeline: tiles t and t+1 in flight (4 gl_lds each per thread).
//   loop t: s_waitcnt vmcnt(4)  (tile t landed; t+1 still flying; FIFO retire)
//           s_barrier            (all waves' tile-t loads visible)
//           ds_read + 16 MFMA    (compiler manages lgkmcnt)
//           s_barrier            (all waves done reading buf before overwrite)
//           stage(t+2) into buf[t&1]
// Last tile waits vmcnt(0). XOR swizzle ((row>>1)&3)<<4 via pre-swizzled
// global source (linear gl_lds dest) + same XOR on ds_read.
__global__ __launch_bounds__(256) void k_gemmB(
    const ushortt* __restrict__ Xb, const ushortt* __restrict__ Wb,
    const float* __restrict__ bias,
    float* __restrict__ Of, ushortt* __restrict__ Ob, const int p)
{
    __shared__ char sA[2][8192];   // 2 x 128 rows x 64B
    __shared__ char sB[2][8192];

    const int t = threadIdx.x;
    const int ln = t & 63;
    const int wv = t >> 6;
    const int wr = wv >> 1, wc = wv & 1;

    // XCD-aware bijective swizzle: 1024 blocks, xcd = orig%8 gets 128 contiguous.
    const int orig = blockIdx.x;
    const int bid = (orig & 7) * 128 + (orig >> 3);
    const int mblk = (bid >> 3) * 128;
    const int nblk = (bid & 7) * 128;

    f32x4 acc[4][4];
#pragma unroll
    for (int i = 0; i < 4; i++)
#pragma unroll
        for (int j = 0; j < 4; j++) acc[i][j] = (f32x4){0.f, 0.f, 0.f, 0.f};

    // staging lane constants (16 rows of 64B per 1KB chunk)
    const int rowIn = ln >> 2;                              // 0..15
    const int srcE  = ((ln & 3) ^ ((ln >> 3) & 3)) << 3;    // bf16 elems, pre-swizzled

    // frag-read lane constants
    const int g   = ln >> 4;
    const int r15 = ln & 15;
    const int sw  = ((r15 >> 1) & 3) << 4;                  // ((row>>1)&3)<<4

    auto stage = [&](int buf, int k0) {
#pragma unroll
        for (int c = 0; c < 2; c++) {
            const int ch = wv * 2 + c;
            const int row = ch * 16 + rowIn;
            gl_lds16(Xb + (size_t)(mblk + row) * E_DIM + k0 + srcE, &sA[buf][ch * 1024]);
            gl_lds16(Wb + (size_t)(nblk + row) * E_DIM + k0 + srcE, &sB[buf][ch * 1024]);
        }
    };

    // prologue: 2 tiles in flight (8 outstanding gl_lds per thread)
    stage(0, 0);
    stage(1, 32);

    for (int tt = 0; tt < 32; tt++) {
        const int cur = tt & 1;
        // wait for tile tt only; tile tt+1's 4 loads may stay in flight
        if (tt < 31) {
            asm volatile("s_waitcnt vmcnt(4)" ::: "memory");
        } else {
            asm volatile("s_waitcnt vmcnt(0)" ::: "memory");
        }
        __builtin_amdgcn_sched_barrier(0);
        __builtin_amdgcn_s_barrier();      // all waves' tile-tt loads visible

        bf16x8 va[4], vb[4];
#pragma unroll
        for (int i = 0; i < 4; i++) {
            const int row = wr * 64 + i * 16 + r15;
            va[i] = *reinterpret_cast<const bf16x8*>(&sA[cur][row * 64 + ((g * 16) ^ sw)]);
        }
#pragma unroll
        for (int j = 0; j < 4; j++) {
            const int n = wc * 64 + j * 16 + r15;
            vb[j] = *reinterpret_cast<const bf16x8*>(&sB[cur][n * 64 + ((g * 16) ^ sw)]);
        }
#pragma unroll
        for (int i = 0; i < 4; i++)
#pragma unroll
            for (int j = 0; j < 4; j++)
                acc[i][j] = __builtin_amdgcn_mfma_f32_16x16x32_bf16(va[i], vb[j], acc[i][j], 0, 0, 0);

        // all waves done READING buf[cur] before anyone overwrites it
        asm volatile("s_waitcnt lgkmcnt(0)" ::: "memory");
        __builtin_amdgcn_sched_barrier(0);
        __builtin_amdgcn_s_barrier();
        __builtin_amdgcn_sched_barrier(0);

        if (tt + 2 < 32) stage(cur, (tt + 2) * 32);
    }

    // ---- epilogue: C row = (lane>>4)*4 + reg, col = lane&15 (m89 mapping) ----
#pragma unroll
    for (int j = 0; j < 4; j++) {
        const int col = nblk + wc * 64 + j * 16 + r15;
        const float bj = bias[col];
#pragma unroll
        for (int i = 0; i < 4; i++) {
            const int row0 = mblk + wr * 64 + i * 16 + g * 4;
#pragma unroll
            for (int r = 0; r < 4; r++) {
                float v = acc[i][j][r] + bj;
                if (p < 2) v = fmaxf(v, 0.0f);
                if (p == 0) Of[(size_t)(row0 + r) * E_DIM + col] = v;
                else        Ob[(size_t)(row0 + r) * E_DIM + col] = f2bf(v);
            }
        }
    }
}

// ---------------- kv partials: pm[ch][head][128][64], pd[ch][head][128] ------
// pm = sum_{l in chunk} sk[l][d]*v[l][m]; pd = sum sk[l][d]. Plain stores.
__global__ __launch_bounds__(256) void k_kv3(
    const ushortt* __restrict__ Kb, const ushortt* __restrict__ Vb,
    float* __restrict__ pm, float* __restrict__ pd)
{
    __shared__ float sk[KV_LT][128];   // feature-mapped K tile
    __shared__ float sv[KV_LT][64];    // V tile

    const int head = blockIdx.x;
    const int b = head >> 4, hh = head & 15;
    const int t = threadIdx.x;
    const int mq = t & 7;              // m base = mq*8
    const int dq = t >> 3;             // d base = dq*4
    const int l0base = blockIdx.y * KV_LCH;

    float acc[4][8];
    float ksum[4];
#pragma unroll
    for (int i = 0; i < 4; i++) {
        ksum[i] = 0.0f;
#pragma unroll
        for (int j = 0; j < 8; j++) acc[i][j] = 0.0f;
    }

    const size_t headoff = (size_t)hh * 64;

    for (int l0 = l0base; l0 < l0base + KV_LCH; l0 += KV_LT) {
        __syncthreads();
#pragma unroll
        for (int i = 0; i < 2; i++) {
            const int j = t + 256 * i;         // 0..511
            const int l = j >> 4;              // 0..31
            const int c4 = (j & 15) << 2;      // 0,4,...,60
            const size_t rowb = ((size_t)(l0 + l) * B_DIM + b) * E_DIM + headoff;
            const uint2 kraw = *reinterpret_cast<const uint2*>(Kb + rowb + c4);
            const uint2 vraw = *reinterpret_cast<const uint2*>(Vb + rowb + c4);
            const float ang = 1.5707963267948966f * (float)(l0 + l + 1) * (1.0f / 4096.0f);
            const float sn = sinf(ang), cs = cosf(ang);
            const float k0 = bf2f((ushortt)(kraw.x & 0xffffu));
            const float k1 = bf2f((ushortt)(kraw.x >> 16));
            const float k2 = bf2f((ushortt)(kraw.y & 0xffffu));
            const float k3 = bf2f((ushortt)(kraw.y >> 16));
            *reinterpret_cast<float4*>(&sk[l][c4]) =
                make_float4(sn * k0, sn * k1, sn * k2, sn * k3);
            *reinterpret_cast<float4*>(&sk[l][64 + c4]) =
                make_float4(cs * k0, cs * k1, cs * k2, cs * k3);
            *reinterpret_cast<float4*>(&sv[l][c4]) =
                make_float4(bf2f((ushortt)(vraw.x & 0xffffu)),
                            bf2f((ushortt)(vraw.x >> 16)),
                            bf2f((ushortt)(vraw.y & 0xffffu)),
                            bf2f((ushortt)(vraw.y >> 16)));
        }
        __syncthreads();
#pragma unroll 8
        for (int l = 0; l < KV_LT; l++) {
            const float4 a4 = *reinterpret_cast<const float4*>(&sk[l][dq << 2]);
            const float4 v0 = *reinterpret_cast<const float4*>(&sv[l][mq << 3]);
            const float4 v1 = *reinterpret_cast<const float4*>(&sv[l][(mq << 3) + 4]);
            const float av[4] = { a4.x, a4.y, a4.z, a4.w };
            const float vv[8] = { v0.x, v0.y, v0.z, v0.w, v1.x, v1.y, v1.z, v1.w };
#pragma unroll
            for (int i = 0; i < 4; i++) {
#pragma unroll
                for (int j = 0; j < 8; j++) acc[i][j] += av[i] * vv[j];
                ksum[i] += av[i];
            }
        }
    }

    float* dstm = pm + ((size_t)blockIdx.y * 64 + head) * 8192;   // 128*64
    float* dstd = pd + ((size_t)blockIdx.y * 64 + head) * 128;
    const int d0 = dq << 2, m0 = mq << 3;
#pragma unroll
    for (int i = 0; i < 4; i++) {
        *reinterpret_cast<float4*>(&dstm[(d0 + i) * 64 + m0]) =
            make_float4(acc[i][0], acc[i][1], acc[i][2], acc[i][3]);
        *reinterpret_cast<float4*>(&dstm[(d0 + i) * 64 + m0 + 4]) =
            make_float4(acc[i][4], acc[i][5], acc[i][6], acc[i][7]);
        if (mq == 0) dstd[d0 + i] = ksum[i];
    }
}

// ---------------- reduce partials: kvm[head][128][64], kvd[head][128] --------
__global__ __launch_bounds__(256) void k_kvred(
    const float* __restrict__ pm, const float* __restrict__ pd,
    float* __restrict__ kvm, float* __restrict__ kvd)
{
    const int bid = blockIdx.x, t = threadIdx.x;
    if (bid < 512) {
        const int g = bid * 256 + t;           // float4 index, 131072 total
        const int head = g >> 11, r = g & 2047;
        float4 s = make_float4(0.f, 0.f, 0.f, 0.f);
#pragma unroll
        for (int c = 0; c < KV_CH; c++) {
            const float4 v = reinterpret_cast<const float4*>(pm)[((size_t)(c * 64 + head) << 11) + r];
            s.x += v.x; s.y += v.y; s.z += v.z; s.w += v.w;
        }
        reinterpret_cast<float4*>(kvm)[g] = s;
    } else {
#pragma unroll
        for (int it = 0; it < 8; it++) {
            const int idx = it * 256 + t;      // float4 index, 2048 total
            const int head = idx >> 5, r = idx & 31;
            float4 s = make_float4(0.f, 0.f, 0.f, 0.f);
#pragma unroll
            for (int c = 0; c < KV_CH; c++) {
                const float4 v = reinterpret_cast<const float4*>(pd)[((size_t)(c * 64 + head) << 5) + r];
                s.x += v.x; s.y += v.y; s.z += v.z; s.w += v.w;
            }
            reinterpret_cast<float4*>(kvd)[idx] = s;
        }
    }
}

// ---------------- attn: out = (q_ . kv) / max(q_ . ksum, eps) ----------------
// Block = (head, 64 l-rows). LDS: skv[128][64] 32KB + skd[128] + sq[64][132]
// (33.8KB) = 66.4KB -> 2 blocks/CU. Thread patch 4 rows x 4 m (16x16 groups).
// In-place safe: block stages its own qout slice, barrier, then overwrites it.
__global__ __launch_bounds__(256) void k_attn3(
    float* qout, const float* __restrict__ kvm, const float* __restrict__ kvd)
{
    __shared__ float skv[128][64];
    __shared__ float skd[128];
    __shared__ float sq[64][132];

    const int t = threadIdx.x;
    const int head = blockIdx.x;           // 0..63
    const int b = head >> 4, hh = head & 15;
    const int l0 = blockIdx.y * 64;

    const float* kvh = kvm + (size_t)head * (128 * 64);

    // stage kv head-tile: 128 rows x 16 float4 (aligned, coalesced)
#pragma unroll
    for (int c = 0; c < 8; c++) {
        const int idx = t + 256 * c;       // 0..2047
        const int d = idx >> 4, m4 = (idx & 15) << 2;
        *reinterpret_cast<float4*>(&skv[d][m4]) =
            *reinterpret_cast<const float4*>(kvh + d * 64 + m4);
    }
    if (t < 128) skd[t] = kvd[(size_t)head * 128 + t];

    // stage 64 q rows with sin/cos feature map folded in
    const size_t qbase = ((size_t)l0 * B_DIM + b) * E_DIM + (size_t)hh * 64;
#pragma unroll
    for (int c = 0; c < 4; c++) {
        const int idx = t + 256 * c;       // 0..1023
        const int l = idx >> 4, q4 = (idx & 15) << 2;
        const float4 v = *reinterpret_cast<const float4*>(
            qout + qbase + (size_t)l * (B_DIM * E_DIM) + q4);
        const float ang = 1.5707963267948966f * (float)(l0 + l + 1) * (1.0f / 4096.0f);
        const float sn = sinf(ang), cs = cosf(ang);
        *reinterpret_cast<float4*>(&sq[l][q4]) =
            make_float4(sn * v.x, sn * v.y, sn * v.z, sn * v.w);
        *reinterpret_cast<float4*>(&sq[l][64 + q4]) =
            make_float4(cs * v.x, cs * v.y, cs * v.z, cs * v.w);
    }
    __syncthreads();

    const int tx = t & 15, ty = t >> 4;
    const int r = ty * 4, m0 = tx * 4;

    float4 acc[4];
    float accd[4];
#pragma unroll
    for (int i = 0; i < 4; i++) {
        acc[i] = make_float4(0.f, 0.f, 0.f, 0.f);
        accd[i] = 0.f;
    }

#pragma unroll 4
    for (int d0 = 0; d0 < 128; d0 += 4) {
        const float4 kd4 = *reinterpret_cast<const float4*>(&skd[d0]);
        float4 qv[4];
#pragma unroll
        for (int i = 0; i < 4; i++)
            qv[i] = *reinterpret_cast<const float4*>(&sq[r + i][d0]);
#pragma unroll
        for (int dd = 0; dd < 4; dd++) {
            const float4 kvv = *reinterpret_cast<const float4*>(&skv[d0 + dd][m0]);
            const float kdv = (dd == 0) ? kd4.x : (dd == 1) ? kd4.y : (dd == 2) ? kd4.z : kd4.w;
#pragma unroll
            for (int i = 0; i < 4; i++) {
                const float qs = (dd == 0) ? qv[i].x : (dd == 1) ? qv[i].y
                               : (dd == 2) ? qv[i].z : qv[i].w;
                acc[i].x += qs * kvv.x;
                acc[i].y += qs * kvv.y;
                acc[i].z += qs * kvv.z;
                acc[i].w += qs * kvv.w;
                accd[i] += qs * kdv;
            }
        }
    }

#pragma unroll
    for (int i = 0; i < 4; i++) {
        const float z = 1.0f / fmaxf(accd[i], 1e-4f);
        float4 vo = make_float4(acc[i].x * z, acc[i].y * z, acc[i].z * z, acc[i].w * z);
        *reinterpret_cast<float4*>(
            qout + qbase + (size_t)(r + i) * (B_DIM * E_DIM) + m0) = vo;
    }
}

extern "C" void kernel_launch(void* const* d_in, const int* in_sizes, int n_in,
                              void* d_out, int out_size, void* d_ws, size_t ws_size,
                              hipStream_t stream) {
    (void)in_sizes; (void)n_in; (void)out_size; (void)ws_size;
    const float* xq = (const float*)d_in[0];
    const float* xk = (const float*)d_in[1];
    const float* xv = (const float*)d_in[2];
    const float* wq = (const float*)d_in[3];
    const float* bq = (const float*)d_in[4];
    const float* wk = (const float*)d_in[5];
    const float* bk = (const float*)d_in[6];
    const float* wv = (const float*)d_in[7];
    const float* bv = (const float*)d_in[8];
    float* out = (float*)d_out;  // 67MB; free as scratch until Q-proj (runs last)

    char* ws = (char*)d_ws;
    // ws (69.24MB): [0,33.5M) Kb / later Xqb ; [33.5M,67.1M) Vb / later Wqb ;
    // [67.1M, +2.13M) Wb (K/V phase) / later kvm+kvd.
    ushortt* Kb  = (ushortt*)(ws);
    ushortt* Vb  = (ushortt*)(ws + 33554432);
    ushortt* Wb  = (ushortt*)(ws + 67108864);
    float*   kvm = (float*)(ws + 67108864);
    float*   kvd = (float*)(ws + 67108864 + 2097152);
    ushortt* Xqb = (ushortt*)(ws);              // over dead Kb
    ushortt* Wqb = (ushortt*)(ws + 33554432);   // over dead Vb

    // d_out scratch: [0,33.5M) Xkb / later pm+pd ; [33.5M,67.1M) Xvb.
    ushortt* Xkb = (ushortt*)d_out;
    ushortt* Xvb = (ushortt*)((char*)d_out + 33554432);
    float*   pm  = (float*)d_out;                              // 16.78MB
    float*   pd  = (float*)((char*)d_out + 16777216);          // 262KB

    dim3 blk(256);
    // K projection
    k_cvtW<<<dim3(1024), blk, 0, stream>>>(wk, Wb);
    k_cvtX<<<dim3(16384), blk, 0, stream>>>(xk, Xkb);
    k_gemmB<<<dim3(1024), blk, 0, stream>>>(Xkb, Wb, bk, (float*)nullptr, Kb, 1);
    // V projection
    k_cvtW<<<dim3(1024), blk, 0, stream>>>(wv, Wb);
    k_cvtX<<<dim3(16384), blk, 0, stream>>>(xv, Xvb);
    k_gemmB<<<dim3(1024), blk, 0, stream>>>(Xvb, Wb, bv, (float*)nullptr, Vb, 2);
    // kv partials (plain stores into d_out) + reduce into ws (over dead Wb)
    k_kv3<<<dim3(64, KV_CH), blk, 0, stream>>>(Kb, Vb, pm, pd);
    k_kvred<<<dim3(513), blk, 0, stream>>>(pm, pd, kvm, kvd);
    // Q projection (scratch in dead Kb/Vb regions; output fills d_out)
    k_cvtW<<<dim3(1024), blk, 0, stream>>>(wq, Wqb);
    k_cvtX<<<dim3(16384), blk, 0, stream>>>(xq, Xqb);
    k_gemmB<<<dim3(1024), blk, 0, stream>>>(Xqb, Wqb, bq, out, (ushortt*)nullptr, 0);
    // attention epilogue, in-place on d_out
    k_attn3<<<dim3(64, 64), blk, 0, stream>>>(out, kvm, kvd);
}

// Round 8
// 525.749 us; speedup vs baseline: 1.0761x; 1.0594x over previous
//
#include <hip/hip_runtime.h>
#include <hip/hip_bf16.h>

// CosformerAttention: L=4096, B=4, E=1024, H=16, HD=64, n=B*H=64 heads.
// Round 15: re-land round-14's 256x256xBK64 8-wave GEMM with defensive fixes
// for the container failure (suspected VGPR-over-256 at 512 threads):
//  - __launch_bounds__(512, 2): pins the <=256 VGPR/wave contract (8-wave
//    block needs 2 waves/SIMD resident).
//  - inner loop restructured: vb[4] preloaded per ks-slice, va read per-i
//    (live fragment regs ~20 instead of ~96).
//  - __align__(16) on LDS buffers (explicit ds_read_b128 alignment).
// Sync skeleton unchanged from race-verified round-13: 2-deep prefetch,
// steady s_waitcnt vmcnt(8) (never 0 until last tile), two raw s_barriers
// per K-step. 128KB LDS dbuf, 3-bit XOR swizzle (slot ^= row&7) via
// pre-swizzled global source + same XOR on ds_read.
//  k_attn3/k_kv3/k_kvred/k_cvtW/k_cvtX: unchanged.

typedef unsigned short ushortt;
typedef unsigned int u32;
typedef __attribute__((ext_vector_type(8))) short bf16x8;
typedef __attribute__((ext_vector_type(4))) float f32x4;

#define L_DIM 4096
#define B_DIM 4
#define E_DIM 1024

#define KV_CH 8                    // L chunks for k_kv3
#define KV_LCH (L_DIM / KV_CH)     // 512 rows per chunk
#define KV_LT 32                   // l-tile rows staged in LDS

__device__ __forceinline__ ushortt f2bf(float f) {
    union { float f; u32 u; } v; v.f = f;
    u32 u = v.u;
    u += 0x7FFFu + ((u >> 16) & 1u);   // round-to-nearest-even
    return (ushortt)(u >> 16);
}
__device__ __forceinline__ float bf2f(ushortt h) {
    union { u32 u; float f; } v; v.u = ((u32)h) << 16;
    return v.f;
}

__device__ __forceinline__ void gl_lds16(const void* g, void* l) {
    __builtin_amdgcn_global_load_lds(
        (const __attribute__((address_space(1))) unsigned int*)g,
        (__attribute__((address_space(3))) unsigned int*)l, 16, 0, 0);
}

// ---------------- f32 -> bf16 converters -------------------------------------
__global__ __launch_bounds__(256) void k_cvtW(
    const float* __restrict__ W, ushortt* __restrict__ Wb)
{
    const int i = (blockIdx.x * 256 + threadIdx.x) * 4;   // 1M elems
    const float4 v = *reinterpret_cast<const float4*>(W + i);
    ushortt o[4] = { f2bf(v.x), f2bf(v.y), f2bf(v.z), f2bf(v.w) };
    *reinterpret_cast<uint2*>(Wb + i) = *reinterpret_cast<uint2*>(o);
}

__global__ __launch_bounds__(256) void k_cvtX(
    const float* __restrict__ X, ushortt* __restrict__ Xb)
{
    const int i = (blockIdx.x * 256 + threadIdx.x) * 4;   // 16.8M elems
    const float4 v = *reinterpret_cast<const float4*>(X + i);
    ushortt o[4] = { f2bf(v.x), f2bf(v.y), f2bf(v.z), f2bf(v.w) };
    *reinterpret_cast<uint2*>(Xb + i) = *reinterpret_cast<uint2*>(o);
}

// ---------------- MFMA projection GEMM: 256x256, BK=64, 8 waves --------------
// Y[m][n] = relu?(sum_k Xb[m][k]*Wb[n][k] + b[n]); M=16384, N=1024, K=1024.
// Grid 256 blocks (64 m-tiles x 4 n-tiles), 512 threads (8 waves, 2M x 4N),
// per-wave output 128x64 = 8x4 fragments of 16x16. 16 K-steps of BK=64,
// each: 2 ks-slices of {4 vb ds_read + 8x(1 va ds_read + 4 MFMA)}.
// LDS: sA/sB = 2buf x 256 rows x 128B = 128KB total. Row slot s (16B slots)
// holds global slot s^(row&7); ds_read applies the same XOR.
// Pipeline: tiles t,t+1 in flight (8 gl_lds/thread each). Steady state
// s_waitcnt vmcnt(8); vmcnt(0) only on the last tile. Bias preloaded BEFORE
// the prologue so pre-loop vmem is strictly older than all staged tiles.
__global__ __launch_bounds__(512, 2) void k_gemm256(
    const ushortt* __restrict__ Xb, const ushortt* __restrict__ Wb,
    const float* __restrict__ bias,
    float* __restrict__ Of, ushortt* __restrict__ Ob, const int p)
{
    __shared__ __align__(16) char sA[2][32768];   // 2 x 256 rows x 128B
    __shared__ __align__(16) char sB[2][32768];

    const int t = threadIdx.x;
    const int ln = t & 63;
    const int wv = t >> 6;          // 0..7
    const int wr = wv >> 2;         // 0..1  M half
    const int wc = wv & 3;          // 0..3  N quarter

    // XCD-bijective swizzle: 256 blocks, 32 contiguous per XCD.
    const int orig = blockIdx.x;
    const int bid = (orig & 7) * 32 + (orig >> 3);
    const int mblk = (bid >> 2) * 256;
    const int nblk = (bid & 3) * 256;

    f32x4 acc[8][4];
#pragma unroll
    for (int i = 0; i < 8; i++)
#pragma unroll
        for (int j = 0; j < 4; j++) acc[i][j] = (f32x4){0.f, 0.f, 0.f, 0.f};

    // staging lane constants: chunk = 8 rows x 128B (1KB); lane covers
    // row = ch*8 + (ln>>3), slot = ln&7; source slot pre-swizzled by row&7.
    const int rowIn = ln >> 3;                         // 0..7
    const int srcE  = ((ln & 7) ^ rowIn) << 3;         // bf16 elems

    // frag-read lane constants
    const int g   = ln >> 4;                           // 0..3
    const int r15 = ln & 15;
    const int sw3 = r15 & 7;                           // row&7 for frag rows

    auto stage = [&](int buf, int k0) {
#pragma unroll
        for (int c = 0; c < 4; c++) {
            const int ch = wv * 4 + c;                 // 0..31
            const int row = ch * 8 + rowIn;            // 0..255
            gl_lds16(Xb + (size_t)(mblk + row) * E_DIM + k0 + srcE, &sA[buf][ch * 1024]);
            gl_lds16(Wb + (size_t)(nblk + row) * E_DIM + k0 + srcE, &sB[buf][ch * 1024]);
        }
    };

    // bias preload (4 vmem, older than all staged tiles -> ledger safe)
    float bj[4];
#pragma unroll
    for (int j = 0; j < 4; j++)
        bj[j] = bias[nblk + wc * 64 + j * 16 + r15];
    __builtin_amdgcn_sched_barrier(0);

    // prologue: 2 tiles in flight (16 gl_lds outstanding per thread)
    stage(0, 0);
    stage(1, 64);

    for (int tt = 0; tt < 16; tt++) {
        const int cur = tt & 1;
        if (tt < 15) {
            asm volatile("s_waitcnt vmcnt(8)" ::: "memory");   // tile tt landed
        } else {
            asm volatile("s_waitcnt vmcnt(0)" ::: "memory");
        }
        __builtin_amdgcn_sched_barrier(0);
        __builtin_amdgcn_s_barrier();      // all waves' tile-tt loads visible

#pragma unroll
        for (int ks = 0; ks < 2; ks++) {
            const int off = ((ks * 4 + g) ^ sw3) << 4;
            bf16x8 vb[4];
#pragma unroll
            for (int j = 0; j < 4; j++) {
                const int row = wc * 64 + j * 16 + r15;
                vb[j] = *reinterpret_cast<const bf16x8*>(&sB[cur][row * 128 + off]);
            }
#pragma unroll
            for (int i = 0; i < 8; i++) {
                const int row = wr * 128 + i * 16 + r15;
                bf16x8 va = *reinterpret_cast<const bf16x8*>(&sA[cur][row * 128 + off]);
#pragma unroll
                for (int j = 0; j < 4; j++)
                    acc[i][j] = __builtin_amdgcn_mfma_f32_16x16x32_bf16(va, vb[j], acc[i][j], 0, 0, 0);
            }
        }

        // all waves done READING buf[cur] before anyone overwrites it
        asm volatile("s_waitcnt lgkmcnt(0)" ::: "memory");
        __builtin_amdgcn_sched_barrier(0);
        __builtin_amdgcn_s_barrier();
        __builtin_amdgcn_sched_barrier(0);

        if (tt + 2 < 16) stage(cur, (tt + 2) * 64);
    }

    // ---- epilogue: C row = (lane>>4)*4 + reg, col = lane&15 (m89 mapping) ----
#pragma unroll
    for (int j = 0; j < 4; j++) {
        const int col = nblk + wc * 64 + j * 16 + r15;
#pragma unroll
        for (int i = 0; i < 8; i++) {
            const int row0 = mblk + wr * 128 + i * 16 + g * 4;
#pragma unroll
            for (int r = 0; r < 4; r++) {
                float v = acc[i][j][r] + bj[j];
                if (p < 2) v = fmaxf(v, 0.0f);
                if (p == 0) Of[(size_t)(row0 + r) * E_DIM + col] = v;
                else        Ob[(size_t)(row0 + r) * E_DIM + col] = f2bf(v);
            }
        }
    }
}

// ---------------- kv partials: pm[ch][head][128][64], pd[ch][head][128] ------
// pm = sum_{l in chunk} sk[l][d]*v[l][m]; pd = sum sk[l][d]. Plain stores.
__global__ __launch_bounds__(256) void k_kv3(
    const ushortt* __restrict__ Kb, const ushortt* __restrict__ Vb,
    float* __restrict__ pm, float* __restrict__ pd)
{
    __shared__ float sk[KV_LT][128];   // feature-mapped K tile
    __shared__ float sv[KV_LT][64];    // V tile

    const int head = blockIdx.x;
    const int b = head >> 4, hh = head & 15;
    const int t = threadIdx.x;
    const int mq = t & 7;              // m base = mq*8
    const int dq = t >> 3;             // d base = dq*4
    const int l0base = blockIdx.y * KV_LCH;

    float acc[4][8];
    float ksum[4];
#pragma unroll
    for (int i = 0; i < 4; i++) {
        ksum[i] = 0.0f;
#pragma unroll
        for (int j = 0; j < 8; j++) acc[i][j] = 0.0f;
    }

    const size_t headoff = (size_t)hh * 64;

    for (int l0 = l0base; l0 < l0base + KV_LCH; l0 += KV_LT) {
        __syncthreads();
#pragma unroll
        for (int i = 0; i < 2; i++) {
            const int j = t + 256 * i;         // 0..511
            const int l = j >> 4;              // 0..31
            const int c4 = (j & 15) << 2;      // 0,4,...,60
            const size_t rowb = ((size_t)(l0 + l) * B_DIM + b) * E_DIM + headoff;
            const uint2 kraw = *reinterpret_cast<const uint2*>(Kb + rowb + c4);
            const uint2 vraw = *reinterpret_cast<const uint2*>(Vb + rowb + c4);
            const float ang = 1.5707963267948966f * (float)(l0 + l + 1) * (1.0f / 4096.0f);
            const float sn = sinf(ang), cs = cosf(ang);
            const float k0 = bf2f((ushortt)(kraw.x & 0xffffu));
            const float k1 = bf2f((ushortt)(kraw.x >> 16));
            const float k2 = bf2f((ushortt)(kraw.y & 0xffffu));
            const float k3 = bf2f((ushortt)(kraw.y >> 16));
            *reinterpret_cast<float4*>(&sk[l][c4]) =
                make_float4(sn * k0, sn * k1, sn * k2, sn * k3);
            *reinterpret_cast<float4*>(&sk[l][64 + c4]) =
                make_float4(cs * k0, cs * k1, cs * k2, cs * k3);
            *reinterpret_cast<float4*>(&sv[l][c4]) =
                make_float4(bf2f((ushortt)(vraw.x & 0xffffu)),
                            bf2f((ushortt)(vraw.x >> 16)),
                            bf2f((ushortt)(vraw.y & 0xffffu)),
                            bf2f((ushortt)(vraw.y >> 16)));
        }
        __syncthreads();
#pragma unroll 8
        for (int l = 0; l < KV_LT; l++) {
            const float4 a4 = *reinterpret_cast<const float4*>(&sk[l][dq << 2]);
            const float4 v0 = *reinterpret_cast<const float4*>(&sv[l][mq << 3]);
            const float4 v1 = *reinterpret_cast<const float4*>(&sv[l][(mq << 3) + 4]);
            const float av[4] = { a4.x, a4.y, a4.z, a4.w };
            const float vv[8] = { v0.x, v0.y, v0.z, v0.w, v1.x, v1.y, v1.z, v1.w };
#pragma unroll
            for (int i = 0; i < 4; i++) {
#pragma unroll
                for (int j = 0; j < 8; j++) acc[i][j] += av[i] * vv[j];
                ksum[i] += av[i];
            }
        }
    }

    float* dstm = pm + ((size_t)blockIdx.y * 64 + head) * 8192;   // 128*64
    float* dstd = pd + ((size_t)blockIdx.y * 64 + head) * 128;
    const int d0 = dq << 2, m0 = mq << 3;
#pragma unroll
    for (int i = 0; i < 4; i++) {
        *reinterpret_cast<float4*>(&dstm[(d0 + i) * 64 + m0]) =
            make_float4(acc[i][0], acc[i][1], acc[i][2], acc[i][3]);
        *reinterpret_cast<float4*>(&dstm[(d0 + i) * 64 + m0 + 4]) =
            make_float4(acc[i][4], acc[i][5], acc[i][6], acc[i][7]);
        if (mq == 0) dstd[d0 + i] = ksum[i];
    }
}

// ---------------- reduce partials: kvm[head][128][64], kvd[head][128] --------
__global__ __launch_bounds__(256) void k_kvred(
    const float* __restrict__ pm, const float* __restrict__ pd,
    float* __restrict__ kvm, float* __restrict__ kvd)
{
    const int bid = blockIdx.x, t = threadIdx.x;
    if (bid < 512) {
        const int g = bid * 256 + t;           // float4 index, 131072 total
        const int head = g >> 11, r = g & 2047;
        float4 s = make_float4(0.f, 0.f, 0.f, 0.f);
#pragma unroll
        for (int c = 0; c < KV_CH; c++) {
            const float4 v = reinterpret_cast<const float4*>(pm)[((size_t)(c * 64 + head) << 11) + r];
            s.x += v.x; s.y += v.y; s.z += v.z; s.w += v.w;
        }
        reinterpret_cast<float4*>(kvm)[g] = s;
    } else {
#pragma unroll
        for (int it = 0; it < 8; it++) {
            const int idx = it * 256 + t;      // float4 index, 2048 total
            const int head = idx >> 5, r = idx & 31;
            float4 s = make_float4(0.f, 0.f, 0.f, 0.f);
#pragma unroll
            for (int c = 0; c < KV_CH; c++) {
                const float4 v = reinterpret_cast<const float4*>(pd)[((size_t)(c * 64 + head) << 5) + r];
                s.x += v.x; s.y += v.y; s.z += v.z; s.w += v.w;
            }
            reinterpret_cast<float4*>(kvd)[idx] = s;
        }
    }
}

// ---------------- attn: out = (q_ . kv) / max(q_ . ksum, eps) ----------------
// Block = (head, 64 l-rows). LDS: skv[128][64] 32KB + skd[128] + sq[64][132]
// (33.8KB) = 66.4KB -> 2 blocks/CU. Thread patch 4 rows x 4 m (16x16 groups).
// In-place safe: block stages its own qout slice, barrier, then overwrites it.
__global__ __launch_bounds__(256) void k_attn3(
    float* qout, const float* __restrict__ kvm, const float* __restrict__ kvd)
{
    __shared__ float skv[128][64];
    __shared__ float skd[128];
    __shared__ float sq[64][132];

    const int t = threadIdx.x;
    const int head = blockIdx.x;           // 0..63
    const int b = head >> 4, hh = head & 15;
    const int l0 = blockIdx.y * 64;

    const float* kvh = kvm + (size_t)head * (128 * 64);

    // stage kv head-tile: 128 rows x 16 float4 (aligned, coalesced)
#pragma unroll
    for (int c = 0; c < 8; c++) {
        const int idx = t + 256 * c;       // 0..2047
        const int d = idx >> 4, m4 = (idx & 15) << 2;
        *reinterpret_cast<float4*>(&skv[d][m4]) =
            *reinterpret_cast<const float4*>(kvh + d * 64 + m4);
    }
    if (t < 128) skd[t] = kvd[(size_t)head * 128 + t];

    // stage 64 q rows with sin/cos feature map folded in
    const size_t qbase = ((size_t)l0 * B_DIM + b) * E_DIM + (size_t)hh * 64;
#pragma unroll
    for (int c = 0; c < 4; c++) {
        const int idx = t + 256 * c;       // 0..1023
        const int l = idx >> 4, q4 = (idx & 15) << 2;
        const float4 v = *reinterpret_cast<const float4*>(
            qout + qbase + (size_t)l * (B_DIM * E_DIM) + q4);
        const float ang = 1.5707963267948966f * (float)(l0 + l + 1) * (1.0f / 4096.0f);
        const float sn = sinf(ang), cs = cosf(ang);
        *reinterpret_cast<float4*>(&sq[l][q4]) =
            make_float4(sn * v.x, sn * v.y, sn * v.z, sn * v.w);
        *reinterpret_cast<float4*>(&sq[l][64 + q4]) =
            make_float4(cs * v.x, cs * v.y, cs * v.z, cs * v.w);
    }
    __syncthreads();

    const int tx = t & 15, ty = t >> 4;
    const int r = ty * 4, m0 = tx * 4;

    float4 acc[4];
    float accd[4];
#pragma unroll
    for (int i = 0; i < 4; i++) {
        acc[i] = make_float4(0.f, 0.f, 0.f, 0.f);
        accd[i] = 0.f;
    }

#pragma unroll 4
    for (int d0 = 0; d0 < 128; d0 += 4) {
        const float4 kd4 = *reinterpret_cast<const float4*>(&skd[d0]);
        float4 qv[4];
#pragma unroll
        for (int i = 0; i < 4; i++)
            qv[i] = *reinterpret_cast<const float4*>(&sq[r + i][d0]);
#pragma unroll
        for (int dd = 0; dd < 4; dd++) {
            const float4 kvv = *reinterpret_cast<const float4*>(&skv[d0 + dd][m0]);
            const float kdv = (dd == 0) ? kd4.x : (dd == 1) ? kd4.y : (dd == 2) ? kd4.z : kd4.w;
#pragma unroll
            for (int i = 0; i < 4; i++) {
                const float qs = (dd == 0) ? qv[i].x : (dd == 1) ? qv[i].y
                               : (dd == 2) ? qv[i].z : qv[i].w;
                acc[i].x += qs * kvv.x;
                acc[i].y += qs * kvv.y;
                acc[i].z += qs * kvv.z;
                acc[i].w += qs * kvv.w;
                accd[i] += qs * kdv;
            }
        }
    }

#pragma unroll
    for (int i = 0; i < 4; i++) {
        const float z = 1.0f / fmaxf(accd[i], 1e-4f);
        float4 vo = make_float4(acc[i].x * z, acc[i].y * z, acc[i].z * z, acc[i].w * z);
        *reinterpret_cast<float4*>(
            qout + qbase + (size_t)(r + i) * (B_DIM * E_DIM) + m0) = vo;
    }
}

extern "C" void kernel_launch(void* const* d_in, const int* in_sizes, int n_in,
                              void* d_out, int out_size, void* d_ws, size_t ws_size,
                              hipStream_t stream) {
    (void)in_sizes; (void)n_in; (void)out_size; (void)ws_size;
    const float* xq = (const float*)d_in[0];
    const float* xk = (const float*)d_in[1];
    const float* xv = (const float*)d_in[2];
    const float* wq = (const float*)d_in[3];
    const float* bq = (const float*)d_in[4];
    const float* wk = (const float*)d_in[5];
    const float* bk = (const float*)d_in[6];
    const float* wv = (const float*)d_in[7];
    const float* bv = (const float*)d_in[8];
    float* out = (float*)d_out;  // 67MB; free as scratch until Q-proj (runs last)

    char* ws = (char*)d_ws;
    // ws (69.24MB): [0,33.5M) Kb / later Xqb ; [33.5M,67.1M) Vb / later Wqb ;
    // [67.1M, +2.13M) Wb (K/V phase) / later kvm+kvd.
    ushortt* Kb  = (ushortt*)(ws);
    ushortt* Vb  = (ushortt*)(ws + 33554432);
    ushortt* Wb  = (ushortt*)(ws + 67108864);
    float*   kvm = (float*)(ws + 67108864);
    float*   kvd = (float*)(ws + 67108864 + 2097152);
    ushortt* Xqb = (ushortt*)(ws);              // over dead Kb
    ushortt* Wqb = (ushortt*)(ws + 33554432);   // over dead Vb

    // d_out scratch: [0,33.5M) Xkb / later pm+pd ; [33.5M,67.1M) Xvb.
    ushortt* Xkb = (ushortt*)d_out;
    ushortt* Xvb = (ushortt*)((char*)d_out + 33554432);
    float*   pm  = (float*)d_out;                              // 16.78MB
    float*   pd  = (float*)((char*)d_out + 16777216);          // 262KB

    dim3 blk(256);
    // K projection
    k_cvtW<<<dim3(1024), blk, 0, stream>>>(wk, Wb);
    k_cvtX<<<dim3(16384), blk, 0, stream>>>(xk, Xkb);
    k_gemm256<<<dim3(256), dim3(512), 0, stream>>>(Xkb, Wb, bk, (float*)nullptr, Kb, 1);
    // V projection
    k_cvtW<<<dim3(1024), blk, 0, stream>>>(wv, Wb);
    k_cvtX<<<dim3(16384), blk, 0, stream>>>(xv, Xvb);
    k_gemm256<<<dim3(256), dim3(512), 0, stream>>>(Xvb, Wb, bv, (float*)nullptr, Vb, 2);
    // kv partials (plain stores into d_out) + reduce into ws (over dead Wb)
    k_kv3<<<dim3(64, KV_CH), blk, 0, stream>>>(Kb, Vb, pm, pd);
    k_kvred<<<dim3(513), blk, 0, stream>>>(pm, pd, kvm, kvd);
    // Q projection (scratch in dead Kb/Vb regions; output fills d_out)
    k_cvtW<<<dim3(1024), blk, 0, stream>>>(wq, Wqb);
    k_cvtX<<<dim3(16384), blk, 0, stream>>>(xq, Xqb);
    k_gemm256<<<dim3(256), dim3(512), 0, stream>>>(Xqb, Wqb, bq, out, (ushortt*)nullptr, 0);
    // attention epilogue, in-place on d_out
    k_attn3<<<dim3(64, 64), blk, 0, stream>>>(out, kvm, kvd);
}